// Round 13
// baseline (134.224 us; speedup 1.0000x reference)
//
#include <hip/hip_runtime.h>

#define IMG_W 512
#define IMG_H 512
#define PLANE_PX (IMG_W * IMG_H)
#define N_ELEMS (48 * PLANE_PX)
#define NTHREADS 256
#define TILEW 54
#define NCT 10                 // 9 full col-tiles + 1 partial (26)
#define NBLK (48 * 16 * NCT)   // 7680
#define RSTR 66                // R row stride in uint2 (64 used)

#define C1f 1.0e-4f
#define C2f 9.0e-4f

typedef _Float16 h2 __attribute__((ext_vector_type(2)));
typedef __fp16 fp16v2 __attribute__((ext_vector_type(2)));

// Packed f16 FMA (v_pk_fma_f16).
__device__ __forceinline__ h2 h2fma(_Float16 w, h2 v, h2 acc) {
    h2 wv = {w, w};
    return __builtin_elementwise_fma(wv, v, acc);
}
__device__ __forceinline__ unsigned int h2bits(h2 v) {
    union { h2 h; unsigned int u; } c; c.h = v; return c.u;
}
__device__ __forceinline__ h2 bits2h(unsigned int u) {
    union { h2 h; unsigned int u; } c; c.u = u; return c.h;
}
// v_cvt_pkrtz_f16_f32 returns __fp16x2; bit-cast to _Float16x2 (same layout).
__device__ __forceinline__ h2 pkrtz(float x, float y) {
    union { fp16v2 f; h2 h; } c;
    c.f = __builtin_amdgcn_cvt_pkrtz(x, y);
    return c.h;
}

__global__ void __launch_bounds__(NTHREADS, 8) ssim_main(
    const float* __restrict__ img1, const float* __restrict__ img2,
    float* __restrict__ partials)
{
    // Vertical-conv results as packed f16: R[row][col] = {(cs,cd),(css,cdd)}.
    __shared__ uint2 R[32 * RSTR];          // 16896 B -> 8 blocks/CU
    __shared__ float wpart[4];

    // Gaussian window (f16 taps for conv).
    constexpr _Float16 Gh[11] = {
        (_Float16)0.00102838f, (_Float16)0.00759876f, (_Float16)0.03600077f,
        (_Float16)0.10936070f, (_Float16)0.21300553f, (_Float16)0.26601173f,
        (_Float16)0.21300553f, (_Float16)0.10936070f, (_Float16)0.03600077f,
        (_Float16)0.00759876f, (_Float16)0.00102838f
    };

    const int tid = threadIdx.x;

    // Work decode + XCD swizzle: XCD (blockIdx&7) owns 6 contiguous planes.
    const int xcd = blockIdx.x & 7;
    const int idx = blockIdx.x >> 3;             // [0,960)
    const int plane = xcd * 6 + idx / 160;
    const int t = idx % 160;
    const int band = t / 10;                     // y-band [0,16), 32 rows each
    const int ct = t - band * 10;                // col-tile [0,10)
    const int tx0 = ct * TILEW;
    const int ty0 = band * 32;
    const float* pa = img1 + (size_t)plane * PLANE_PX;
    const float* pb = img2 + (size_t)plane * PLANE_PX;

    // ================= Phase A: vertical conv, lane = staged column =========
    const int c = tid & 63;                      // staged col
    const int g = tid >> 6;                      // wave = row-group
    const int gx = tx0 - 5 + c;
    const int cgx = min(max(gx, 0), IMG_W - 1);
    const _Float16 ml = ((unsigned)gx < (unsigned)IMG_W) ? (_Float16)1.f
                                                         : (_Float16)0.f;
    const h2 mlv = {ml, ml};
    const int ry0 = ty0 + g * 8 - 5;

    // Batch all 36 loads (coalesced 256B rows) -- the fence below keeps them
    // issued back-to-back ahead of the conv (36-deep MLP; progressive vmcnt).
    float av[18], bv[18];
    const bool intY = (ry0 >= 0) && (ry0 + 18 <= IMG_H);     // wave-uniform
    if (intY) {
        const float* qa = pa + (size_t)ry0 * IMG_W + cgx;
        const float* qb = pb + (size_t)ry0 * IMG_W + cgx;
#pragma unroll
        for (int j = 0; j < 18; ++j) {
            av[j] = qa[j * IMG_W];
            bv[j] = qb[j * IMG_W];
        }
    } else {
#pragma unroll
        for (int j = 0; j < 18; ++j) {
            int ry = ry0 + j;
            int ryc = min(max(ry, 0), IMG_H - 1);
            float rm = ((unsigned)ry < (unsigned)IMG_H) ? 1.f : 0.f;
            av[j] = pa[(size_t)ryc * IMG_W + cgx] * rm;
            bv[j] = pb[(size_t)ryc * IMG_W + cgx] * rm;
        }
    }
    __asm__ __volatile__("" ::: "memory");       // loads stay ahead of conv

    h2 asd[8], asq[8];
#pragma unroll
    for (int k = 0; k < 8; ++k) { asd[k] = (h2)(_Float16)0; asq[k] = (h2)(_Float16)0; }
#pragma unroll
    for (int j = 0; j < 18; ++j) {
        // (s,d) packed to f16 in ONE inst (v_cvt_pkrtz_f16_f32).
        h2 sd = pkrtz(av[j] + bv[j], av[j] - bv[j]);
        h2 sq = sd * sd;                         // v_pk_mul_f16
#pragma unroll
        for (int k = 0; k < 8; ++k) {
            int tt = j - k;
            if (tt >= 0 && tt < 11) {            // folds at compile time
                asd[k] = h2fma(Gh[tt], sd, asd[k]);
                asq[k] = h2fma(Gh[tt], sq, asq[k]);
            }
        }
    }
#pragma unroll
    for (int k = 0; k < 8; ++k) {
        h2 wsd = asd[k] * mlv;                   // column mask (once, linear)
        h2 wsq = asq[k] * mlv;
        R[(g * 8 + k) * RSTR + c] = make_uint2(h2bits(wsd), h2bits(wsq));
    }
    __syncthreads();

    // ================= Phase B: horizontal conv + SSIM =======================
    // 32 rows x 8 col-groups x 7 outputs; zero unpack (pk_fma_f16 on LDS bits).
    const int y = tid >> 3;
    const int cg = tid & 7;
    const int c0 = cg * 7;
    const uint2* row = R + y * RSTR;

    h2 osd[7], osq[7];
#pragma unroll
    for (int o = 0; o < 7; ++o) { osd[o] = (h2)(_Float16)0; osq[o] = (h2)(_Float16)0; }

#pragma unroll
    for (int j = 0; j < 17; ++j) {
        // c0+j <= 49+16 = 65 < RSTR: cols 64..65 are junk-but-finite and feed
        // only cg==7's masked outputs (o>=5), discarded by `valid` below.
        uint2 p = row[min(c0 + j, 65)];          // ds_read_b64
        h2 vsd = bits2h(p.x);
        h2 vsq = bits2h(p.y);
#pragma unroll
        for (int o = 0; o < 7; ++o) {
            int tt = j - o;
            if (tt >= 0 && tt < 11) {
                osd[o] = h2fma(Gh[tt], vsd, osd[o]);
                osq[o] = h2fma(Gh[tt], vsq, osq[o]);
            }
        }
    }

    float local = 0.f;
#pragma unroll
    for (int o = 0; o < 7; ++o) {
        float cs  = (float)osd[o].x, cd  = (float)osd[o].y;
        float css = (float)osq[o].x, cdd = (float)osq[o].y;
        float cs2 = cs * cs, cd2 = cd * cd;
        float mu12 = 0.25f * (cs2 - cd2);        // mu1*mu2
        float musq = 0.50f * (cs2 + cd2);        // mu1^2 + mu2^2
        float e12  = 0.25f * (css - cdd);        // E[ab]
        float esum = 0.50f * (css + cdd);        // E[a^2] + E[b^2]
        float num = (2.f * mu12 + C1f) * (2.f * (e12 - mu12) + C2f);
        float den = (musq + C1f) * ((esum - musq) + C2f);
        float sv = num * __builtin_amdgcn_rcpf(den);
        bool valid = (c0 + o < TILEW) && (tx0 + c0 + o < IMG_W);
        local += valid ? sv : 0.f;
    }

    // ================= Block reduction -> one partial ========================
#pragma unroll
    for (int off = 32; off > 0; off >>= 1) local += __shfl_down(local, off, 64);
    if ((tid & 63) == 0) wpart[tid >> 6] = local;
    __syncthreads();
    if (tid == 0)
        partials[blockIdx.x] = wpart[0] + wpart[1] + wpart[2] + wpart[3];
}

__global__ void ssim_final(const float* __restrict__ partials,
                           float* __restrict__ out)
{
    __shared__ float wp[4];
    const int tid = threadIdx.x;
    const float4* p4 = (const float4*)partials;  // 7680/4 = 1920 float4
    float s = 0.f;
    for (int i = tid; i < NBLK / 4; i += NTHREADS) {
        float4 v = p4[i];
        s += (v.x + v.y) + (v.z + v.w);
    }
#pragma unroll
    for (int off = 32; off > 0; off >>= 1) s += __shfl_down(s, off, 64);
    if ((tid & 63) == 0) wp[tid >> 6] = s;
    __syncthreads();
    if (tid == 0)
        out[0] = 1.0f - (wp[0] + wp[1] + wp[2] + wp[3]) * (1.0f / (float)N_ELEMS);
}

extern "C" void kernel_launch(void* const* d_in, const int* in_sizes, int n_in,
                              void* d_out, int out_size, void* d_ws, size_t ws_size,
                              hipStream_t stream) {
    const float* img1 = (const float*)d_in[0];
    const float* img2 = (const float*)d_in[1];
    float* out = (float*)d_out;
    float* partials = (float*)d_ws;     // NBLK floats = 30.7 KB

    ssim_main<<<NBLK, NTHREADS, 0, stream>>>(img1, img2, partials);
    ssim_final<<<1, NTHREADS, 0, stream>>>(partials, out);
}